// Round 8
// baseline (1364.991 us; speedup 1.0000x reference)
//
#include <hip/hip_runtime.h>
#include <hip/hip_bf16.h>
#include <float.h>
#include <math.h>

#define HW 16384
#define NBATCH 4
#define DIM 256
#define NEGV (-1e30f)
#define NPP 160

// ---- workspace byte offsets ----
#define OFF_CHAN_SUM 0        // 256 f32
#define OFF_CHAN_SQ  1024
#define OFF_MEAN     2048
#define OFF_ISTD     3072
#define OFF_S1       4096     // 4*256 f32
#define OFF_S0       8192
#define OFF_CF       12288    // 4 int
#define OFF_CB       12304
#define OFF_BL       12320    // 8 f32
#define OFF_INCF     12352
#define OFF_QBUF     16384    // 8*256 f32
#define OFF_MCLS     40960    // 65536 int (0=none,1=fg,2=bg)
#define OFF_SELIDX   303104   // 8*160 int
#define OFF_SELW     308224   // 8*160 f32
#define OFF_ROWS     313344   // 8*160*256 f32 (ends 1,624,064)

// ============ masks + counts ============
__global__ void k_mask(const float* __restrict__ po, const float* __restrict__ pa,
                       const float* __restrict__ unc, const int* __restrict__ lab,
                       int* __restrict__ mcls, int* __restrict__ cf, int* __restrict__ cb) {
  int g = blockIdx.x * 256 + threadIdx.x;          // 0..65535
  int b = g >> 14;
  int i = g & (HW - 1);
  float o0 = po[(size_t)(b*2+0)*HW + i];
  float o1 = po[(size_t)(b*2+1)*HW + i];
  float a0 = pa[(size_t)(b*2+0)*HW + i];
  float a1 = pa[(size_t)(b*2+1)*HW + i];
  bool rel = ((o1 > o0) == (a1 > a0));             // argmax tie -> idx0, strict >
  bool valid = rel && (unc[g] > 0.5f);
  int l = lab[g];
  int cls = valid ? ((l == 1) ? 1 : 2) : 0;
  mcls[g] = cls;
  if (cls == 1) atomicAdd(&cf[b], 1);
  if (cls == 2) atomicAdd(&cb[b], 1);
}

// ============ tiled fp32 matmul for BN stats: raw = feat^T @ w1^T ============
__global__ __launch_bounds__(256) void k_matmul(
    const float* __restrict__ feat, const float* __restrict__ w1,
    float* __restrict__ chanSum, float* __restrict__ chanSq) {
  __shared__ __align__(16) float As[64*68];
  __shared__ __align__(16) float Bs[64*68];
  __shared__ float cA[64], cB[64];
  int tid = threadIdx.x;
  int rt = blockIdx.x;
  int ct = blockIdx.y;
  int b  = rt >> 8;
  int i0 = (rt & 255) << 6;
  int c0 = ct << 6;
  int tx = tid & 15, ty = tid >> 4;
  float acc[4][4] = {{0.f,0.f,0.f,0.f},{0.f,0.f,0.f,0.f},{0.f,0.f,0.f,0.f},{0.f,0.f,0.f,0.f}};
  for (int kc = 0; kc < 4; ++kc) {
    int d0 = kc << 6;
    #pragma unroll
    for (int it = 0; it < 4; ++it) {
      int k  = it*16 + (tid >> 4);
      int rq = tid & 15;
      float4 v = *(const float4*)&feat[((size_t)(b*DIM + d0 + k))*HW + i0 + rq*4];
      *(float4*)&As[k*68 + rq*4] = v;
    }
    #pragma unroll
    for (int it = 0; it < 4; ++it) {
      int col = it*16 + (tid >> 4);
      int kq  = tid & 15;
      float4 v = *(const float4*)&w1[(size_t)(c0 + col)*DIM + d0 + kq*4];
      Bs[(kq*4+0)*68 + col] = v.x;
      Bs[(kq*4+1)*68 + col] = v.y;
      Bs[(kq*4+2)*68 + col] = v.z;
      Bs[(kq*4+3)*68 + col] = v.w;
    }
    __syncthreads();
    #pragma unroll
    for (int k = 0; k < 64; ++k) {
      float4 av = *(const float4*)&As[k*68 + ty*4];
      float4 bv = *(const float4*)&Bs[k*68 + tx*4];
      float aa[4] = {av.x, av.y, av.z, av.w};
      float bb[4] = {bv.x, bv.y, bv.z, bv.w};
      #pragma unroll
      for (int rr = 0; rr < 4; ++rr)
        #pragma unroll
        for (int cc = 0; cc < 4; ++cc)
          acc[rr][cc] += aa[rr]*bb[cc];
    }
    __syncthreads();
  }
  if (tid < 64) { cA[tid] = 0.f; cB[tid] = 0.f; }
  __syncthreads();
  float s[4] = {0,0,0,0}, q[4] = {0,0,0,0};
  #pragma unroll
  for (int rr = 0; rr < 4; ++rr)
    #pragma unroll
    for (int cc = 0; cc < 4; ++cc) { float v = acc[rr][cc]; s[cc] += v; q[cc] += v*v; }
  #pragma unroll
  for (int cc = 0; cc < 4; ++cc) {
    atomicAdd(&cA[tx*4+cc], s[cc]);
    atomicAdd(&cB[tx*4+cc], q[cc]);
  }
  __syncthreads();
  if (tid < 64) {
    atomicAdd(&chanSum[c0 + tid], cA[tid]);
    atomicAdd(&chanSq[c0 + tid],  cB[tid]);
  }
}

// ============ finalize BN stats ============
__global__ void k_stats(const float* __restrict__ chanSum, const float* __restrict__ chanSq,
                        float* __restrict__ meanr, float* __restrict__ istd) {
  int e = threadIdx.x;
  const float n = (float)(NBATCH * HW);
  float m = chanSum[e] / n;
  float v = chanSq[e] / n - m*m;
  meanr[e] = m;
  istd[e]  = 1.0f / sqrtf(v + 1e-5f);
}

// ============ masked relu-bn channel sums S1/S0 (inline validity) ============
__global__ __launch_bounds__(256) void k_sums(
    const float* __restrict__ feat, const float* __restrict__ w1,
    const float* __restrict__ gamma, const float* __restrict__ beta,
    const float* __restrict__ meanr, const float* __restrict__ istd,
    const float* __restrict__ po, const float* __restrict__ pa,
    const float* __restrict__ unc, const int* __restrict__ lab,
    float* __restrict__ S1, float* __restrict__ S0) {
  int g = blockIdx.x;                       // 0..65535
  __shared__ int cls_sh;
  __shared__ __align__(16) float fr[DIM];
  int e = threadIdx.x;
  int b = g >> 14, i = g & (HW - 1);
  if (e == 0) {
    float o0 = po[(size_t)(b*2+0)*HW + i];
    float o1 = po[(size_t)(b*2+1)*HW + i];
    float a0 = pa[(size_t)(b*2+0)*HW + i];
    float a1 = pa[(size_t)(b*2+1)*HW + i];
    bool rel = ((o1 > o0) == (a1 > a0));
    bool valid = rel && (unc[g] > 0.5f);
    int l = lab[g];
    cls_sh = valid ? ((l == 1) ? 1 : 2) : 0;
  }
  __syncthreads();
  int cls = cls_sh;
  if (cls == 0) return;                     // block-uniform
  fr[e] = feat[((size_t)(b*DIM + e))*HW + i];
  __syncthreads();
  float acc = 0.f;
  const float4* f4 = (const float4*)fr;
  const float4* w4 = (const float4*)&w1[(size_t)e*DIM];
  #pragma unroll 8
  for (int d = 0; d < DIM/4; ++d) {
    float4 a = f4[d], w = w4[d];
    acc += a.x*w.x + a.y*w.y + a.z*w.z + a.w*w.w;
  }
  float bn = gamma[e]*istd[e]*(acc - meanr[e]) + beta[e];
  float v = bn > 0.f ? bn : 0.f;
  atomicAdd((cls == 1) ? &S1[b*DIM + e] : &S0[b*DIM + e], v);
}

// ============ selection (stable top-k, exact tie-break) ============
__global__ __launch_bounds__(256) void k_select(
    const int* __restrict__ mcls,
    const float* __restrict__ r_anc, const float* __restrict__ r_pos, const float* __restrict__ r_neg,
    const float* __restrict__ unc,
    int* __restrict__ selIdx, float* __restrict__ selW) {
  __shared__ float swv[4]; __shared__ int swi[4];
  __shared__ int   cIdx[128];
  __shared__ float cValf[128];
  int tid  = threadIdx.x;
  int task = blockIdx.x;
  int pair = task / 3, which = task % 3;
  int b = pair >> 1, c = pair & 1;
  int wantA = (c == 0) ? 1 : 2;
  int want  = (which == 2) ? (3 - wantA) : wantA;
  const int* mc = mcls + (size_t)b * HW;
  const float* r = (which == 0) ? r_anc : (which == 1 ? r_pos : r_neg);
  r += (size_t)(b*2 + c) * HW;

  float key[64];
  #pragma unroll
  for (int j = 0; j < 64; ++j) {
    int i = tid + j*256;
    key[j] = (mc[i] == want) ? r[i] : NEGV;
  }
  int K1 = (which == 0) ? 32 : 128;
  int outBase = pair*NPP + (which == 0 ? 0 : (which == 1 ? 32 : 96));

  for (int it = 0; it < K1; ++it) {
    float bv = -FLT_MAX; int bi = 0x7FFFFFFF;
    #pragma unroll
    for (int j = 0; j < 64; ++j) {
      if (key[j] > bv) { bv = key[j]; bi = tid + j*256; }
    }
    #pragma unroll
    for (int off = 32; off > 0; off >>= 1) {
      float v2 = __shfl_down(bv, off, 64);
      int   i2 = __shfl_down(bi, off, 64);
      if (v2 > bv || (v2 == bv && i2 < bi)) { bv = v2; bi = i2; }
    }
    if ((tid & 63) == 0) { swv[tid >> 6] = bv; swi[tid >> 6] = bi; }
    __syncthreads();
    float fv = swv[0]; int fi = swi[0];
    #pragma unroll
    for (int w = 1; w < 4; ++w) {
      float v2 = swv[w]; int i2 = swi[w];
      if (v2 > fv || (v2 == fv && i2 < fi)) { fv = v2; fi = i2; }
    }
    __syncthreads();
    if (tid == 0) {
      if (which == 0) { selIdx[outBase + it] = fi; selW[outBase + it] = (fv >= 0.f) ? 1.f : 0.f; }
      else            { cIdx[it] = fi;             cValf[it] = (fv >= 0.f) ? 1.f : 0.f; }
    }
    #pragma unroll
    for (int j = 0; j < 64; ++j) {
      if (fi == tid + j*256) key[j] = -FLT_MAX;
    }
  }
  if (which == 0) return;
  __syncthreads();

  // stage 2: top-64 of 128 candidates by (uncertainty desc, candidate pos asc)
  float k2 = -FLT_MAX;
  if (tid < 128) k2 = (cValf[tid] > 0.f) ? unc[(size_t)b*HW + cIdx[tid]] : NEGV;
  for (int it = 0; it < 64; ++it) {
    float bv = k2; int bi = (tid < 128) ? tid : 0x7FFFFFFF;
    #pragma unroll
    for (int off = 32; off > 0; off >>= 1) {
      float v2 = __shfl_down(bv, off, 64);
      int   i2 = __shfl_down(bi, off, 64);
      if (v2 > bv || (v2 == bv && i2 < bi)) { bv = v2; bi = i2; }
    }
    if ((tid & 63) == 0) { swv[tid >> 6] = bv; swi[tid >> 6] = bi; }
    __syncthreads();
    float fv = swv[0]; int fi = swi[0];
    #pragma unroll
    for (int w = 1; w < 4; ++w) {
      float v2 = swv[w]; int i2 = swi[w];
      if (v2 > fv || (v2 == fv && i2 < fi)) { fv = v2; fi = i2; }
    }
    __syncthreads();
    if (tid == 0) {
      selIdx[outBase + it] = cIdx[fi];
      selW[outBase + it]   = cValf[fi];
    }
    if (tid == fi) k2 = -FLT_MAX;
    (void)fv;
  }
}

// ============ gathered proj rows ============
__global__ __launch_bounds__(256) void k_rowproj(
    const float* __restrict__ feat, const float* __restrict__ w1, const float* __restrict__ w2,
    const float* __restrict__ b2, const float* __restrict__ gamma, const float* __restrict__ beta,
    const float* __restrict__ meanr, const float* __restrict__ istd,
    const int* __restrict__ selIdx, float* __restrict__ rows) {
  __shared__ __align__(16) float fr[DIM];
  __shared__ __align__(16) float rl[DIM];
  __shared__ float red[256];
  int slot = blockIdx.x;
  int pair = slot / NPP;
  int b = pair >> 1;
  int i = selIdx[slot];
  int e = threadIdx.x;
  fr[e] = feat[((size_t)(b*DIM + e))*HW + i];
  __syncthreads();
  float acc = 0.f;
  {
    const float4* f4 = (const float4*)fr;
    const float4* w4 = (const float4*)&w1[(size_t)e*DIM];
    #pragma unroll 8
    for (int d = 0; d < DIM/4; ++d) {
      float4 a = f4[d], w = w4[d];
      acc += a.x*w.x + a.y*w.y + a.z*w.z + a.w*w.w;
    }
  }
  float bn = gamma[e]*istd[e]*(acc - meanr[e]) + beta[e];
  rl[e] = bn > 0.f ? bn : 0.f;
  __syncthreads();
  float pj = b2[e];
  {
    const float4* f4 = (const float4*)rl;
    const float4* w4 = (const float4*)&w2[(size_t)e*DIM];
    #pragma unroll 8
    for (int d = 0; d < DIM/4; ++d) {
      float4 a = f4[d], w = w4[d];
      pj += a.x*w.x + a.y*w.y + a.z*w.z + a.w*w.w;
    }
  }
  red[e] = pj*pj;
  __syncthreads();
  for (int off = 128; off > 0; off >>= 1) {
    if (e < off) red[e] += red[e+off];
    __syncthreads();
  }
  float sc = 1.f / fmaxf(sqrtf(red[0]), 1e-12f);
  rows[(size_t)slot*DIM + e] = pj * sc;
}

// ============ per-(b,c) pair loss ============
__global__ __launch_bounds__(256) void k_pair(
    const float* __restrict__ rows, const float* __restrict__ selW,
    const int* __restrict__ cf, const int* __restrict__ cb,
    float* __restrict__ BL, float* __restrict__ INCF) {
  __shared__ float q[32*257];
  __shared__ float pacc[256], nacc[256];
  __shared__ float red[64];
  int pair = blockIdx.x;
  int b = pair >> 1, c = pair & 1;
  int tid = threadIdx.x;
  for (int l = tid; l < 32*DIM; l += 256) {
    int r = l >> 8, d = l & 255;
    q[r*257 + d] = rows[((size_t)pair*NPP + r)*DIM + d];
  }
  __syncthreads();
  int g = tid >> 5, r = tid & 31;
  float ap = 0.f, an = 0.f;
  for (int so = 0; so < 8; ++so) {
    int s = so*8 + g;
    const float* Pr = &rows[((size_t)pair*NPP + 32 + s)*DIM];
    const float* Nr = &rows[((size_t)pair*NPP + 96 + s)*DIM];
    float dp = 0.f, dn = 0.f;
    for (int d = 0; d < DIM; ++d) {
      float qv = q[r*257 + d];
      dp += Pr[d]*qv;
      dn += Nr[d]*qv;
    }
    ap += expf(dp*10.f) * selW[pair*NPP + 32 + s];
    an += expf(dn*10.f) * selW[pair*NPP + 96 + s];
  }
  pacc[tid] = ap; nacc[tid] = an;
  __syncthreads();
  if (tid < 32) {
    float p = 0.f, n = 0.f;
    for (int gg = 0; gg < 8; ++gg) { p += pacc[gg*32 + tid]; n += nacc[gg*32 + tid]; }
    int amC = (c == 0) ? cf[b] : cb[b];
    int nmC = (c == 0) ? cb[b] : cf[b];
    bool inc = (amC >= 1) && (nmC >= 1);
    if (!inc) p += 1.f;
    float per = -logf(p / (p + n + 1e-8f));
    float af = selW[pair*NPP + tid];
    red[tid]      = per*af;
    red[32 + tid] = af;
  }
  __syncthreads();
  if (tid == 0) {
    float s = 0.f, sa = 0.f;
    for (int rr = 0; rr < 32; ++rr) { s += red[rr]; sa += red[32+rr]; }
    int amC = (c == 0) ? cf[b] : cb[b];
    int nmC = (c == 0) ? cb[b] : cf[b];
    bool inc = (amC >= 1) && (nmC >= 1);
    float bl = s / fmaxf(sa, 1.f);
    BL[pair]   = inc ? bl : 0.f;
    INCF[pair] = inc ? 1.f : 0.f;
  }
}

// ============ normalized prototypes ============
__global__ __launch_bounds__(64) void k_proto(
    const float* __restrict__ S1, const float* __restrict__ S0,
    const int* __restrict__ cf, const int* __restrict__ cb,
    const float* __restrict__ w2, const float* __restrict__ b2,
    float* __restrict__ qbuf) {
  int b = blockIdx.x >> 1, side = blockIdx.x & 1;
  int l = threadIdx.x;
  const float* S = (side == 0) ? &S1[b*DIM] : &S0[b*DIM];
  float cnt = (float)((side == 0) ? cf[b] : cb[b]);
  float m[4]; float n2p = 0.f;
  #pragma unroll
  for (int k = 0; k < 4; ++k) {
    int e = l + 64*k;
    float acc = 0.f;
    const float* w2r = &w2[(size_t)e*DIM];
    for (int d = 0; d < DIM; ++d) acc += S[d]*w2r[d];
    float mv = (acc + cnt*b2[e]) / fmaxf(cnt, 1.f);
    m[k] = mv; n2p += mv*mv;
  }
  #pragma unroll
  for (int off = 32; off > 0; off >>= 1) n2p += __shfl_down(n2p, off, 64);
  float n2 = __shfl(n2p, 0, 64);
  float sc = 1.f / fmaxf(sqrtf(n2), 1e-12f);
  #pragma unroll
  for (int k = 0; k < 4; ++k)
    qbuf[(size_t)(side*4 + b)*DIM + l + 64*k] = m[k]*sc;
}

// ============ global loss + final combine (single wave) ============
// d_out is a FLOAT32 buffer (established rounds 0-7): write f32 scalars.
__global__ __launch_bounds__(64) void k_glob(
    const float* __restrict__ qbuf,
    const int* __restrict__ cf, const int* __restrict__ cb,
    const float* __restrict__ BL, const float* __restrict__ INCF,
    float* __restrict__ out) {
  int l = threadIdx.x;
  float qf[4][4], qb[4][4];
  #pragma unroll
  for (int b = 0; b < 4; ++b)
    #pragma unroll
    for (int k = 0; k < 4; ++k) {
      qf[b][k] = qbuf[(size_t)b*DIM + l + 64*k];
      qb[b][k] = qbuf[(size_t)(4 + b)*DIM + l + 64*k];
    }
  float pd[24];
  #pragma unroll
  for (int j = 0; j < 4; ++j)
    #pragma unroll
    for (int b = 0; b < 4; ++b) {
      float s = 0.f;
      #pragma unroll
      for (int k = 0; k < 4; ++k) s += qb[j][k]*qf[b][k];
      pd[j*4 + b] = s;                       // qb[j] . qf[b]
    }
  #pragma unroll
  for (int b = 0; b < 4; ++b) {
    float s1 = 0.f, s2 = 0.f;
    #pragma unroll
    for (int k = 0; k < 4; ++k) { s1 += qf[b][k]*qf[b][k]; s2 += qb[b][k]*qb[b][k]; }
    pd[16 + b] = s1; pd[20 + b] = s2;
  }
  #pragma unroll
  for (int t = 0; t < 24; ++t)
    #pragma unroll
    for (int off = 32; off > 0; off >>= 1)
      pd[t] += __shfl_down(pd[t], off, 64);
  if (l == 0) {
    bool vg[4]; float vgs = 0.f;
    for (int b = 0; b < 4; ++b) {
      vg[b] = (cf[b] >= 1) && (cb[b] >= 1);
      if (vg[b]) vgs += 1.f;
    }
    float gsum = 0.f;
    for (int b = 0; b < 4; ++b) {
      float nf = 0.f, nb = 0.f;
      for (int j = 0; j <= b; ++j) if (vg[j]) {
        nf += expf(10.f*pd[j*4 + b]);        // exp(qb[j].qf[b]/TAU)
        nb += expf(10.f*pd[b*4 + j]);        // exp(qf[j].qb[b]/TAU)
      }
      float pf = expf(10.f*pd[16 + b]);
      float pb = expf(10.f*pd[20 + b]);
      float lg = -logf(pf/(pf + nf + 1e-8f)) - logf(pb/(pb + nb + 1e-8f));
      if (vg[b]) gsum += lg;
    }
    float l_global = gsum / fmaxf(vgs, 1.f);
    float bls = 0.f, incs = 0.f;
    for (int p = 0; p < 8; ++p) { bls += BL[p]; incs += INCF[p]; }
    float l_local = bls / fmaxf(incs, 1.f);
    out[0] = l_local + 0.5f*l_global;
    out[1] = l_local;
    out[2] = l_global;
  }
}

extern "C" void kernel_launch(void* const* d_in, const int* in_sizes, int n_in,
                              void* d_out, int out_size, void* d_ws, size_t ws_size,
                              hipStream_t stream) {
  const float* feat     = (const float*)d_in[0];
  const int*   labels   = (const int*)  d_in[1];
  const float* prob_ori = (const float*)d_in[2];
  const float* prob_aug = (const float*)d_in[3];
  const float* unc      = (const float*)d_in[4];
  const float* r_anc    = (const float*)d_in[5];
  const float* r_pos    = (const float*)d_in[6];
  const float* r_neg    = (const float*)d_in[7];
  const float* w1       = (const float*)d_in[8];
  // d_in[9] = b1: cancels inside BN (mean subtraction), unused
  const float* gamma    = (const float*)d_in[10];
  const float* beta     = (const float*)d_in[11];
  const float* w2       = (const float*)d_in[12];
  const float* b2       = (const float*)d_in[13];

  char* ws = (char*)d_ws;
  float* chanSum = (float*)(ws + OFF_CHAN_SUM);
  float* chanSq  = (float*)(ws + OFF_CHAN_SQ);
  float* meanr   = (float*)(ws + OFF_MEAN);
  float* istd    = (float*)(ws + OFF_ISTD);
  float* S1      = (float*)(ws + OFF_S1);
  float* S0      = (float*)(ws + OFF_S0);
  int*   cf      = (int*)  (ws + OFF_CF);
  int*   cb      = (int*)  (ws + OFF_CB);
  float* BLp     = (float*)(ws + OFF_BL);
  float* INCp    = (float*)(ws + OFF_INCF);
  float* qbuf    = (float*)(ws + OFF_QBUF);
  int*   mclsp   = (int*)  (ws + OFF_MCLS);
  int*   selIdx  = (int*)  (ws + OFF_SELIDX);
  float* selW    = (float*)(ws + OFF_SELW);
  float* rowsbuf = (float*)(ws + OFF_ROWS);

  hipMemsetAsync(d_ws, 0, 16384, stream);  // zero all atomic accumulators

  k_mask<<<256, 256, 0, stream>>>(prob_ori, prob_aug, unc, labels, mclsp, cf, cb);

  dim3 gmm(1024, 4);
  k_matmul<<<gmm, 256, 0, stream>>>(feat, w1, chanSum, chanSq);
  k_stats<<<1, 256, 0, stream>>>(chanSum, chanSq, meanr, istd);

  k_sums<<<65536, 256, 0, stream>>>(feat, w1, gamma, beta, meanr, istd,
                                    prob_ori, prob_aug, unc, labels, S1, S0);

  k_select<<<24, 256, 0, stream>>>(mclsp, r_anc, r_pos, r_neg, unc, selIdx, selW);

  k_rowproj<<<1280, 256, 0, stream>>>(feat, w1, w2, b2, gamma, beta, meanr, istd,
                                      selIdx, rowsbuf);

  k_pair<<<8, 256, 0, stream>>>(rowsbuf, selW, cf, cb, BLp, INCp);

  k_proto<<<8, 64, 0, stream>>>(S1, S0, cf, cb, w2, b2, qbuf);

  k_glob<<<1, 64, 0, stream>>>(qbuf, cf, cb, BLp, INCp, (float*)d_out);
}

// Round 9
// 1022.710 us; speedup vs baseline: 1.3347x; 1.3347x over previous
//
#include <hip/hip_runtime.h>
#include <hip/hip_bf16.h>
#include <float.h>
#include <math.h>

#define HW 16384
#define NBATCH 4
#define DIM 256
#define NEGV (-1e30f)
#define NPP 160

// ---- workspace byte offsets ----
#define OFF_CHAN_SUM 0        // 256 f32
#define OFF_CHAN_SQ  1024
#define OFF_MEAN     2048
#define OFF_ISTD     3072
#define OFF_S1       4096     // 4*256 f32
#define OFF_S0       8192
#define OFF_CF       12288    // 4 int
#define OFF_CB       12304
#define OFF_BL       12320    // 8 f32
#define OFF_INCF     12352
#define OFF_QBUF     16384    // 8*256 f32
#define OFF_MCLS     40960    // 65536 int (0=none,1=fg,2=bg)
#define OFF_SELIDX   303104   // 8*160 int
#define OFF_SELW     308224   // 8*160 f32
#define OFF_ROWS     313344   // 8*160*256 f32 (ends 1,624,064)

// ============ masks + counts ============
__global__ void k_mask(const float* __restrict__ po, const float* __restrict__ pa,
                       const float* __restrict__ unc, const int* __restrict__ lab,
                       int* __restrict__ mcls, int* __restrict__ cf, int* __restrict__ cb) {
  int g = blockIdx.x * 256 + threadIdx.x;          // 0..65535
  int b = g >> 14;
  int i = g & (HW - 1);
  float o0 = po[(size_t)(b*2+0)*HW + i];
  float o1 = po[(size_t)(b*2+1)*HW + i];
  float a0 = pa[(size_t)(b*2+0)*HW + i];
  float a1 = pa[(size_t)(b*2+1)*HW + i];
  bool rel = ((o1 > o0) == (a1 > a0));             // argmax tie -> idx0, strict >
  bool valid = rel && (unc[g] > 0.5f);
  int l = lab[g];
  int cls = valid ? ((l == 1) ? 1 : 2) : 0;
  mcls[g] = cls;
  if (cls == 1) atomicAdd(&cf[b], 1);
  if (cls == 2) atomicAdd(&cb[b], 1);
}

// ============ tiled fp32 matmul: raw = feat^T @ w1^T ============
// MODE 0: accumulate per-channel sum / sumsq of raw (BN stats)
// MODE 1: bn+relu, accumulate masked channel sums S1/S0 (replaces k_sums:
//         same math as the gather kernel but with coalesced feat loads and
//         the matmul's compute reused — k_sums was 522 us latency-bound)
template<int MODE>
__global__ __launch_bounds__(256) void k_matmul(
    const float* __restrict__ feat, const float* __restrict__ w1,
    float* __restrict__ chanSum, float* __restrict__ chanSq,
    const float* __restrict__ meanr, const float* __restrict__ istd,
    const float* __restrict__ gamma, const float* __restrict__ beta,
    const int* __restrict__ mcls,
    float* __restrict__ S1, float* __restrict__ S0) {
  __shared__ __align__(16) float As[64*68];  // [k][row] stride 68
  __shared__ __align__(16) float Bs[64*68];  // [k][col]
  __shared__ float cA[64], cB[64];
  int tid = threadIdx.x;
  int rt = blockIdx.x;              // 0..1023 row tiles (64 pixels each)
  int ct = blockIdx.y;              // 0..3 col tiles
  int b  = rt >> 8;
  int i0 = (rt & 255) << 6;
  int c0 = ct << 6;
  int tx = tid & 15, ty = tid >> 4;
  float acc[4][4] = {{0.f,0.f,0.f,0.f},{0.f,0.f,0.f,0.f},{0.f,0.f,0.f,0.f},{0.f,0.f,0.f,0.f}};
  for (int kc = 0; kc < 4; ++kc) {
    int d0 = kc << 6;
    #pragma unroll
    for (int it = 0; it < 4; ++it) {
      int k  = it*16 + (tid >> 4);
      int rq = tid & 15;
      float4 v = *(const float4*)&feat[((size_t)(b*DIM + d0 + k))*HW + i0 + rq*4];
      *(float4*)&As[k*68 + rq*4] = v;
    }
    #pragma unroll
    for (int it = 0; it < 4; ++it) {
      int col = it*16 + (tid >> 4);
      int kq  = tid & 15;
      float4 v = *(const float4*)&w1[(size_t)(c0 + col)*DIM + d0 + kq*4];
      Bs[(kq*4+0)*68 + col] = v.x;
      Bs[(kq*4+1)*68 + col] = v.y;
      Bs[(kq*4+2)*68 + col] = v.z;
      Bs[(kq*4+3)*68 + col] = v.w;
    }
    __syncthreads();
    #pragma unroll
    for (int k = 0; k < 64; ++k) {
      float4 av = *(const float4*)&As[k*68 + ty*4];
      float4 bv = *(const float4*)&Bs[k*68 + tx*4];
      float aa[4] = {av.x, av.y, av.z, av.w};
      float bb[4] = {bv.x, bv.y, bv.z, bv.w};
      #pragma unroll
      for (int rr = 0; rr < 4; ++rr)
        #pragma unroll
        for (int cc = 0; cc < 4; ++cc)
          acc[rr][cc] += aa[rr]*bb[cc];
    }
    __syncthreads();
  }
  if (tid < 64) { cA[tid] = 0.f; cB[tid] = 0.f; }
  __syncthreads();
  if (MODE == 0) {
    float s[4] = {0,0,0,0}, q[4] = {0,0,0,0};
    #pragma unroll
    for (int rr = 0; rr < 4; ++rr)
      #pragma unroll
      for (int cc = 0; cc < 4; ++cc) { float v = acc[rr][cc]; s[cc] += v; q[cc] += v*v; }
    #pragma unroll
    for (int cc = 0; cc < 4; ++cc) {
      atomicAdd(&cA[tx*4+cc], s[cc]);
      atomicAdd(&cB[tx*4+cc], q[cc]);
    }
    __syncthreads();
    if (tid < 64) {
      atomicAdd(&chanSum[c0 + tid], cA[tid]);
      atomicAdd(&chanSq[c0 + tid],  cB[tid]);
    }
  } else {
    float A[4], M[4], Bt[4];
    #pragma unroll
    for (int cc = 0; cc < 4; ++cc) {
      int c = c0 + tx*4 + cc;
      A[cc] = gamma[c]*istd[c]; M[cc] = meanr[c]; Bt[cc] = beta[c];
    }
    float s1[4] = {0,0,0,0}, s0[4] = {0,0,0,0};
    #pragma unroll
    for (int rr = 0; rr < 4; ++rr) {
      int g = rt*64 + ty*4 + rr;     // global row == b*HW + i
      int cls = mcls[g];
      if (cls == 0) continue;
      #pragma unroll
      for (int cc = 0; cc < 4; ++cc) {
        float v = A[cc]*(acc[rr][cc] - M[cc]) + Bt[cc];
        v = v > 0.f ? v : 0.f;
        if (cls == 1) s1[cc] += v; else s0[cc] += v;
      }
    }
    #pragma unroll
    for (int cc = 0; cc < 4; ++cc) {
      atomicAdd(&cA[tx*4+cc], s1[cc]);
      atomicAdd(&cB[tx*4+cc], s0[cc]);
    }
    __syncthreads();
    if (tid < 64) {
      atomicAdd(&S1[b*DIM + c0 + tid], cA[tid]);
      atomicAdd(&S0[b*DIM + c0 + tid], cB[tid]);
    }
  }
}

// ============ finalize BN stats ============
__global__ void k_stats(const float* __restrict__ chanSum, const float* __restrict__ chanSq,
                        float* __restrict__ meanr, float* __restrict__ istd) {
  int e = threadIdx.x;
  const float n = (float)(NBATCH * HW);
  float m = chanSum[e] / n;
  float v = chanSq[e] / n - m*m;
  meanr[e] = m;
  istd[e]  = 1.0f / sqrtf(v + 1e-5f);
}

// ============ selection (stable top-k, exact tie-break) ============
__global__ __launch_bounds__(256) void k_select(
    const int* __restrict__ mcls,
    const float* __restrict__ r_anc, const float* __restrict__ r_pos, const float* __restrict__ r_neg,
    const float* __restrict__ unc,
    int* __restrict__ selIdx, float* __restrict__ selW) {
  __shared__ float swv[4]; __shared__ int swi[4];
  __shared__ int   cIdx[128];
  __shared__ float cValf[128];
  int tid  = threadIdx.x;
  int task = blockIdx.x;
  int pair = task / 3, which = task % 3;
  int b = pair >> 1, c = pair & 1;
  int wantA = (c == 0) ? 1 : 2;
  int want  = (which == 2) ? (3 - wantA) : wantA;
  const int* mc = mcls + (size_t)b * HW;
  const float* r = (which == 0) ? r_anc : (which == 1 ? r_pos : r_neg);
  r += (size_t)(b*2 + c) * HW;

  float key[64];
  #pragma unroll
  for (int j = 0; j < 64; ++j) {
    int i = tid + j*256;
    key[j] = (mc[i] == want) ? r[i] : NEGV;
  }
  int K1 = (which == 0) ? 32 : 128;
  int outBase = pair*NPP + (which == 0 ? 0 : (which == 1 ? 32 : 96));

  for (int it = 0; it < K1; ++it) {
    float bv = -FLT_MAX; int bi = 0x7FFFFFFF;
    #pragma unroll
    for (int j = 0; j < 64; ++j) {
      if (key[j] > bv) { bv = key[j]; bi = tid + j*256; }
    }
    #pragma unroll
    for (int off = 32; off > 0; off >>= 1) {
      float v2 = __shfl_down(bv, off, 64);
      int   i2 = __shfl_down(bi, off, 64);
      if (v2 > bv || (v2 == bv && i2 < bi)) { bv = v2; bi = i2; }
    }
    if ((tid & 63) == 0) { swv[tid >> 6] = bv; swi[tid >> 6] = bi; }
    __syncthreads();
    float fv = swv[0]; int fi = swi[0];
    #pragma unroll
    for (int w = 1; w < 4; ++w) {
      float v2 = swv[w]; int i2 = swi[w];
      if (v2 > fv || (v2 == fv && i2 < fi)) { fv = v2; fi = i2; }
    }
    __syncthreads();
    if (tid == 0) {
      if (which == 0) { selIdx[outBase + it] = fi; selW[outBase + it] = (fv >= 0.f) ? 1.f : 0.f; }
      else            { cIdx[it] = fi;             cValf[it] = (fv >= 0.f) ? 1.f : 0.f; }
    }
    #pragma unroll
    for (int j = 0; j < 64; ++j) {
      if (fi == tid + j*256) key[j] = -FLT_MAX;
    }
  }
  if (which == 0) return;
  __syncthreads();

  // stage 2: top-64 of 128 candidates by (uncertainty desc, candidate pos asc)
  float k2 = -FLT_MAX;
  if (tid < 128) k2 = (cValf[tid] > 0.f) ? unc[(size_t)b*HW + cIdx[tid]] : NEGV;
  for (int it = 0; it < 64; ++it) {
    float bv = k2; int bi = (tid < 128) ? tid : 0x7FFFFFFF;
    #pragma unroll
    for (int off = 32; off > 0; off >>= 1) {
      float v2 = __shfl_down(bv, off, 64);
      int   i2 = __shfl_down(bi, off, 64);
      if (v2 > bv || (v2 == bv && i2 < bi)) { bv = v2; bi = i2; }
    }
    if ((tid & 63) == 0) { swv[tid >> 6] = bv; swi[tid >> 6] = bi; }
    __syncthreads();
    float fv = swv[0]; int fi = swi[0];
    #pragma unroll
    for (int w = 1; w < 4; ++w) {
      float v2 = swv[w]; int i2 = swi[w];
      if (v2 > fv || (v2 == fv && i2 < fi)) { fv = v2; fi = i2; }
    }
    __syncthreads();
    if (tid == 0) {
      selIdx[outBase + it] = cIdx[fi];
      selW[outBase + it]   = cValf[fi];
    }
    if (tid == fi) k2 = -FLT_MAX;
    (void)fv;
  }
}

// ============ gathered proj rows ============
__global__ __launch_bounds__(256) void k_rowproj(
    const float* __restrict__ feat, const float* __restrict__ w1, const float* __restrict__ w2,
    const float* __restrict__ b2, const float* __restrict__ gamma, const float* __restrict__ beta,
    const float* __restrict__ meanr, const float* __restrict__ istd,
    const int* __restrict__ selIdx, float* __restrict__ rows) {
  __shared__ __align__(16) float fr[DIM];
  __shared__ __align__(16) float rl[DIM];
  __shared__ float red[256];
  int slot = blockIdx.x;
  int pair = slot / NPP;
  int b = pair >> 1;
  int i = selIdx[slot];
  int e = threadIdx.x;
  fr[e] = feat[((size_t)(b*DIM + e))*HW + i];
  __syncthreads();
  float acc = 0.f;
  {
    const float4* f4 = (const float4*)fr;
    const float4* w4 = (const float4*)&w1[(size_t)e*DIM];
    #pragma unroll 8
    for (int d = 0; d < DIM/4; ++d) {
      float4 a = f4[d], w = w4[d];
      acc += a.x*w.x + a.y*w.y + a.z*w.z + a.w*w.w;
    }
  }
  float bn = gamma[e]*istd[e]*(acc - meanr[e]) + beta[e];
  rl[e] = bn > 0.f ? bn : 0.f;
  __syncthreads();
  float pj = b2[e];
  {
    const float4* f4 = (const float4*)rl;
    const float4* w4 = (const float4*)&w2[(size_t)e*DIM];
    #pragma unroll 8
    for (int d = 0; d < DIM/4; ++d) {
      float4 a = f4[d], w = w4[d];
      pj += a.x*w.x + a.y*w.y + a.z*w.z + a.w*w.w;
    }
  }
  red[e] = pj*pj;
  __syncthreads();
  for (int off = 128; off > 0; off >>= 1) {
    if (e < off) red[e] += red[e+off];
    __syncthreads();
  }
  float sc = 1.f / fmaxf(sqrtf(red[0]), 1e-12f);
  rows[(size_t)slot*DIM + e] = pj * sc;
}

// ============ per-(b,c) pair loss ============
__global__ __launch_bounds__(256) void k_pair(
    const float* __restrict__ rows, const float* __restrict__ selW,
    const int* __restrict__ cf, const int* __restrict__ cb,
    float* __restrict__ BL, float* __restrict__ INCF) {
  __shared__ float q[32*257];
  __shared__ float pacc[256], nacc[256];
  __shared__ float red[64];
  int pair = blockIdx.x;
  int b = pair >> 1, c = pair & 1;
  int tid = threadIdx.x;
  for (int l = tid; l < 32*DIM; l += 256) {
    int r = l >> 8, d = l & 255;
    q[r*257 + d] = rows[((size_t)pair*NPP + r)*DIM + d];
  }
  __syncthreads();
  int g = tid >> 5, r = tid & 31;
  float ap = 0.f, an = 0.f;
  for (int so = 0; so < 8; ++so) {
    int s = so*8 + g;
    const float* Pr = &rows[((size_t)pair*NPP + 32 + s)*DIM];
    const float* Nr = &rows[((size_t)pair*NPP + 96 + s)*DIM];
    float dp = 0.f, dn = 0.f;
    for (int d = 0; d < DIM; ++d) {
      float qv = q[r*257 + d];
      dp += Pr[d]*qv;
      dn += Nr[d]*qv;
    }
    ap += expf(dp*10.f) * selW[pair*NPP + 32 + s];
    an += expf(dn*10.f) * selW[pair*NPP + 96 + s];
  }
  pacc[tid] = ap; nacc[tid] = an;
  __syncthreads();
  if (tid < 32) {
    float p = 0.f, n = 0.f;
    for (int gg = 0; gg < 8; ++gg) { p += pacc[gg*32 + tid]; n += nacc[gg*32 + tid]; }
    int amC = (c == 0) ? cf[b] : cb[b];
    int nmC = (c == 0) ? cb[b] : cf[b];
    bool inc = (amC >= 1) && (nmC >= 1);
    if (!inc) p += 1.f;
    float per = -logf(p / (p + n + 1e-8f));
    float af = selW[pair*NPP + tid];
    red[tid]      = per*af;
    red[32 + tid] = af;
  }
  __syncthreads();
  if (tid == 0) {
    float s = 0.f, sa = 0.f;
    for (int rr = 0; rr < 32; ++rr) { s += red[rr]; sa += red[32+rr]; }
    int amC = (c == 0) ? cf[b] : cb[b];
    int nmC = (c == 0) ? cb[b] : cf[b];
    bool inc = (amC >= 1) && (nmC >= 1);
    float bl = s / fmaxf(sa, 1.f);
    BL[pair]   = inc ? bl : 0.f;
    INCF[pair] = inc ? 1.f : 0.f;
  }
}

// ============ normalized prototypes ============
__global__ __launch_bounds__(64) void k_proto(
    const float* __restrict__ S1, const float* __restrict__ S0,
    const int* __restrict__ cf, const int* __restrict__ cb,
    const float* __restrict__ w2, const float* __restrict__ b2,
    float* __restrict__ qbuf) {
  int b = blockIdx.x >> 1, side = blockIdx.x & 1;
  int l = threadIdx.x;
  const float* S = (side == 0) ? &S1[b*DIM] : &S0[b*DIM];
  float cnt = (float)((side == 0) ? cf[b] : cb[b]);
  float m[4]; float n2p = 0.f;
  #pragma unroll
  for (int k = 0; k < 4; ++k) {
    int e = l + 64*k;
    float acc = 0.f;
    const float* w2r = &w2[(size_t)e*DIM];
    for (int d = 0; d < DIM; ++d) acc += S[d]*w2r[d];
    float mv = (acc + cnt*b2[e]) / fmaxf(cnt, 1.f);
    m[k] = mv; n2p += mv*mv;
  }
  #pragma unroll
  for (int off = 32; off > 0; off >>= 1) n2p += __shfl_down(n2p, off, 64);
  float n2 = __shfl(n2p, 0, 64);
  float sc = 1.f / fmaxf(sqrtf(n2), 1e-12f);
  #pragma unroll
  for (int k = 0; k < 4; ++k)
    qbuf[(size_t)(side*4 + b)*DIM + l + 64*k] = m[k]*sc;
}

// ============ global loss + final combine (single wave; f32 out) ============
__global__ __launch_bounds__(64) void k_glob(
    const float* __restrict__ qbuf,
    const int* __restrict__ cf, const int* __restrict__ cb,
    const float* __restrict__ BL, const float* __restrict__ INCF,
    float* __restrict__ out) {
  int l = threadIdx.x;
  float qf[4][4], qb[4][4];
  #pragma unroll
  for (int b = 0; b < 4; ++b)
    #pragma unroll
    for (int k = 0; k < 4; ++k) {
      qf[b][k] = qbuf[(size_t)b*DIM + l + 64*k];
      qb[b][k] = qbuf[(size_t)(4 + b)*DIM + l + 64*k];
    }
  float pd[24];
  #pragma unroll
  for (int j = 0; j < 4; ++j)
    #pragma unroll
    for (int b = 0; b < 4; ++b) {
      float s = 0.f;
      #pragma unroll
      for (int k = 0; k < 4; ++k) s += qb[j][k]*qf[b][k];
      pd[j*4 + b] = s;                       // qb[j] . qf[b]
    }
  #pragma unroll
  for (int b = 0; b < 4; ++b) {
    float s1 = 0.f, s2 = 0.f;
    #pragma unroll
    for (int k = 0; k < 4; ++k) { s1 += qf[b][k]*qf[b][k]; s2 += qb[b][k]*qb[b][k]; }
    pd[16 + b] = s1; pd[20 + b] = s2;
  }
  #pragma unroll
  for (int t = 0; t < 24; ++t)
    #pragma unroll
    for (int off = 32; off > 0; off >>= 1)
      pd[t] += __shfl_down(pd[t], off, 64);
  if (l == 0) {
    bool vg[4]; float vgs = 0.f;
    for (int b = 0; b < 4; ++b) {
      vg[b] = (cf[b] >= 1) && (cb[b] >= 1);
      if (vg[b]) vgs += 1.f;
    }
    float gsum = 0.f;
    for (int b = 0; b < 4; ++b) {
      float nf = 0.f, nb = 0.f;
      for (int j = 0; j <= b; ++j) if (vg[j]) {
        nf += expf(10.f*pd[j*4 + b]);
        nb += expf(10.f*pd[b*4 + j]);
      }
      float pf = expf(10.f*pd[16 + b]);
      float pb = expf(10.f*pd[20 + b]);
      float lg = -logf(pf/(pf + nf + 1e-8f)) - logf(pb/(pb + nb + 1e-8f));
      if (vg[b]) gsum += lg;
    }
    float l_global = gsum / fmaxf(vgs, 1.f);
    float bls = 0.f, incs = 0.f;
    for (int p = 0; p < 8; ++p) { bls += BL[p]; incs += INCF[p]; }
    float l_local = bls / fmaxf(incs, 1.f);
    out[0] = l_local + 0.5f*l_global;
    out[1] = l_local;
    out[2] = l_global;
  }
}

extern "C" void kernel_launch(void* const* d_in, const int* in_sizes, int n_in,
                              void* d_out, int out_size, void* d_ws, size_t ws_size,
                              hipStream_t stream) {
  const float* feat     = (const float*)d_in[0];
  const int*   labels   = (const int*)  d_in[1];
  const float* prob_ori = (const float*)d_in[2];
  const float* prob_aug = (const float*)d_in[3];
  const float* unc      = (const float*)d_in[4];
  const float* r_anc    = (const float*)d_in[5];
  const float* r_pos    = (const float*)d_in[6];
  const float* r_neg    = (const float*)d_in[7];
  const float* w1       = (const float*)d_in[8];
  // d_in[9] = b1: cancels inside BN (mean subtraction), unused
  const float* gamma    = (const float*)d_in[10];
  const float* beta     = (const float*)d_in[11];
  const float* w2       = (const float*)d_in[12];
  const float* b2       = (const float*)d_in[13];

  char* ws = (char*)d_ws;
  float* chanSum = (float*)(ws + OFF_CHAN_SUM);
  float* chanSq  = (float*)(ws + OFF_CHAN_SQ);
  float* meanr   = (float*)(ws + OFF_MEAN);
  float* istd    = (float*)(ws + OFF_ISTD);
  float* S1      = (float*)(ws + OFF_S1);
  float* S0      = (float*)(ws + OFF_S0);
  int*   cf      = (int*)  (ws + OFF_CF);
  int*   cb      = (int*)  (ws + OFF_CB);
  float* BLp     = (float*)(ws + OFF_BL);
  float* INCp    = (float*)(ws + OFF_INCF);
  float* qbuf    = (float*)(ws + OFF_QBUF);
  int*   mclsp   = (int*)  (ws + OFF_MCLS);
  int*   selIdx  = (int*)  (ws + OFF_SELIDX);
  float* selW    = (float*)(ws + OFF_SELW);
  float* rowsbuf = (float*)(ws + OFF_ROWS);

  hipMemsetAsync(d_ws, 0, 16384, stream);  // zero all atomic accumulators

  k_mask<<<256, 256, 0, stream>>>(prob_ori, prob_aug, unc, labels, mclsp, cf, cb);

  dim3 gmm(1024, 4);
  k_matmul<0><<<gmm, 256, 0, stream>>>(feat, w1, chanSum, chanSq,
                                       meanr, istd, gamma, beta, mclsp, S1, S0);
  k_stats<<<1, 256, 0, stream>>>(chanSum, chanSq, meanr, istd);

  k_matmul<1><<<gmm, 256, 0, stream>>>(feat, w1, chanSum, chanSq,
                                       meanr, istd, gamma, beta, mclsp, S1, S0);

  k_select<<<24, 256, 0, stream>>>(mclsp, r_anc, r_pos, r_neg, unc, selIdx, selW);

  k_rowproj<<<1280, 256, 0, stream>>>(feat, w1, w2, b2, gamma, beta, meanr, istd,
                                      selIdx, rowsbuf);

  k_pair<<<8, 256, 0, stream>>>(rowsbuf, selW, cf, cb, BLp, INCp);

  k_proto<<<8, 64, 0, stream>>>(S1, S0, cf, cb, w2, b2, qbuf);

  k_glob<<<1, 64, 0, stream>>>(qbuf, cf, cb, BLp, INCp, (float*)d_out);
}